// Round 5
// baseline (581.940 us; speedup 1.0000x reference)
//
#include <hip/hip_runtime.h>

#define NN 100000
#define NE 1600000
#define DIM 64
#define NL 3
#define SLOPE 0.2f

#define BSH 9                      // 512 nodes per bucket
#define NBUCK ((NN + 511) >> BSH)  // 196
#define EPT 16
#define TILE (256 * EPT)  // 4096 edges per partition tile

static __device__ __forceinline__ float lrelu(float x) { return x > 0.f ? x : SLOPE * x; }

// ---------------- CSR build: LDS-binned two-level counting sort ----------------

// per-block LDS histogram over dst buckets, one global atomic per block x bucket
__global__ __launch_bounds__(256) void k_bucket_hist(const int* __restrict__ ei, int* __restrict__ bcnt) {
    __shared__ int h[256];
    int t = threadIdx.x;
    h[t] = 0;
    __syncthreads();
    for (int e = blockIdx.x * 256 + t; e < NE; e += 256 * 256) atomicAdd(&h[ei[NE + e] >> BSH], 1);
    __syncthreads();
    if (t < NBUCK && h[t]) atomicAdd(&bcnt[t], h[t]);
}

__global__ void k_bucket_scan(const int* __restrict__ bcnt, int* __restrict__ bbase, int* __restrict__ bcur,
                              int* __restrict__ offs) {
    __shared__ int sm[256];
    int t = threadIdx.x;
    sm[t] = (t < NBUCK) ? bcnt[t] : 0;
    __syncthreads();
    for (int off = 1; off < 256; off <<= 1) {
        int x = (t >= off) ? sm[t - off] : 0;
        __syncthreads();
        sm[t] += x;
        __syncthreads();
    }
    if (t < NBUCK) {
        int ex = (t == 0) ? 0 : sm[t - 1];
        bbase[t] = ex;
        bcur[t] = ex;
    }
    if (t == 0) {
        bbase[NBUCK] = NE;
        offs[NN] = NE;
    }
}

// rank tile edges per bucket in LDS, reorder tile so same-bucket edges are contiguous,
// claim global space (1 atomic per bucket per tile), copy out coalesced.
__global__ __launch_bounds__(256) void k_partition(const int* __restrict__ ei, int* __restrict__ bcur,
                                                   int2* __restrict__ pairs) {
    __shared__ int2 tile[TILE];
    __shared__ int cnt[256], ofsx[256], gdel[256], sm[256];
    int t = threadIdx.x;
    int ts = blockIdx.x * TILE;
    int tilecnt = NE - ts;
    if (tilecnt > TILE) tilecnt = TILE;
    cnt[t] = 0;
    __syncthreads();
    int srcv[EPT], dstv[EPT], rk[EPT];
#pragma unroll
    for (int k = 0; k < EPT; k++) {
        int e = ts + k * 256 + t;
        if (e < NE) {
            srcv[k] = ei[e];
            dstv[k] = ei[NE + e];
            rk[k] = atomicAdd(&cnt[dstv[k] >> BSH], 1);
        } else {
            rk[k] = -1;
        }
    }
    __syncthreads();
    sm[t] = cnt[t];
    __syncthreads();
    for (int off = 1; off < 256; off <<= 1) {
        int x = (t >= off) ? sm[t - off] : 0;
        __syncthreads();
        sm[t] += x;
        __syncthreads();
    }
    ofsx[t] = (t == 0) ? 0 : sm[t - 1];
    __syncthreads();
#pragma unroll
    for (int k = 0; k < EPT; k++) {
        if (rk[k] >= 0) tile[ofsx[dstv[k] >> BSH] + rk[k]] = make_int2(srcv[k], dstv[k]);
    }
    if (t < NBUCK && cnt[t]) gdel[t] = atomicAdd(&bcur[t], cnt[t]) - ofsx[t];
    __syncthreads();
    for (int i = t; i < tilecnt; i += 256) {
        int2 p = tile[i];
        pairs[gdel[p.y >> BSH] + i] = p;
    }
}

// one block per bucket: per-node counts + scan in LDS, then scatter src into the
// bucket's contiguous csr segment (L2-resident). Emits global offs coalesced.
__global__ __launch_bounds__(256) void k_node_csr(const int2* __restrict__ pairs, const int* __restrict__ bbase,
                                                  int* __restrict__ offs, int* __restrict__ csr) {
    __shared__ int deg[512], sofs[512], scur[512], sm[256];
    int t = threadIdx.x;
    int b = blockIdx.x;
    int nodeBase = b << BSH;
    int nNodes = NN - nodeBase;
    if (nNodes > 512) nNodes = 512;
    deg[t] = 0;
    deg[t + 256] = 0;
    __syncthreads();
    int ebeg = bbase[b], eend = bbase[b + 1];
    for (int i = ebeg + t; i < eend; i += 256) atomicAdd(&deg[pairs[i].y - nodeBase], 1);
    __syncthreads();
    int a0 = deg[2 * t], a1 = deg[2 * t + 1];
    sm[t] = a0 + a1;
    __syncthreads();
    for (int off = 1; off < 256; off <<= 1) {
        int x = (t >= off) ? sm[t - off] : 0;
        __syncthreads();
        sm[t] += x;
        __syncthreads();
    }
    int base = (t == 0) ? 0 : sm[t - 1];
    sofs[2 * t] = base;
    sofs[2 * t + 1] = base + a0;
    scur[2 * t] = 0;
    scur[2 * t + 1] = 0;
    __syncthreads();
    for (int n = t; n < nNodes; n += 256) offs[nodeBase + n] = ebeg + sofs[n];
    for (int i = ebeg + t; i < eend; i += 256) {
        int2 p = pairs[i];
        int ln = p.y - nodeBase;
        int r = atomicAdd(&scur[ln], 1);
        csr[ebeg + sofs[ln] + r] = p.x;
    }
}

// ---------------- per-layer passes ----------------

// wave per node: hw = h @ W, alpha_s = hw . a_src, alpha_d = hw . a_dst.
// h-row accessed with wave-uniform indices -> compiler scalarizes to s_load +
// v_fmac with SGPR broadcast operand (no readlane chain).
__global__ __launch_bounds__(256) void k_transform(const float* __restrict__ h, const float* __restrict__ W,
                                                   const float* __restrict__ avs, const float* __restrict__ avd,
                                                   float* __restrict__ hw, float* __restrict__ als,
                                                   float* __restrict__ ald) {
    int t = threadIdx.x, wave = t >> 6, lane = t & 63;
    float wreg[64];  // W[:, lane] held in registers
#pragma unroll
    for (int k = 0; k < 64; k++) wreg[k] = W[k * 64 + lane];
    float asl = avs[lane], adl = avd[lane];
    int nw = gridDim.x * 4;
    for (int i = blockIdx.x * 4 + wave; i < NN; i += nw) {
        const float* __restrict__ hrow = h + (size_t)i * 64;  // wave-uniform
        float a0 = 0.f, a1 = 0.f, a2 = 0.f, a3 = 0.f;
#pragma unroll
        for (int k = 0; k < 64; k += 4) {
            a0 = fmaf(hrow[k], wreg[k], a0);
            a1 = fmaf(hrow[k + 1], wreg[k + 1], a1);
            a2 = fmaf(hrow[k + 2], wreg[k + 2], a2);
            a3 = fmaf(hrow[k + 3], wreg[k + 3], a3);
        }
        float hv = (a0 + a1) + (a2 + a3);
        hw[(size_t)i * 64 + lane] = hv;
        float ps = hv * asl, pd = hv * adl;
#pragma unroll
        for (int off = 32; off; off >>= 1) {
            ps += __shfl_xor(ps, off);
            pd += __shfl_xor(pd, off);
        }
        if (lane == 0) {
            als[i] = ps;
            ald[i] = pd;
        }
    }
}

// wave per dst node. Phase 1: lanes = edges (coalesced csr load, als gather, shfl
// softmax reductions). Phase 2: quad-packed gather — quad q of 16 lanes handles edge
// j+q, each lane loads float4 of the row (1 dwordx4 instr fetches 4 full rows/wave).
// Self loop deferred to the end with weight exp(e_self - m_final).
__global__ __launch_bounds__(256) void k_aggregate(const float* __restrict__ hw, const float* __restrict__ als,
                                                   const float* __restrict__ ald, const int* __restrict__ offs,
                                                   const int* __restrict__ csr, const float* __restrict__ bv,
                                                   float* __restrict__ out) {
    int t = threadIdx.x, wave = t >> 6, lane = t & 63;
    int i = blockIdx.x * 4 + wave;
    if (i >= NN) return;
    int q = lane >> 4, c = lane & 15;
    float ad = ald[i];
    float eself = lrelu(als[i] + ad);
    float m = eself;
    float s = 0.f;
    float4 acc = make_float4(0.f, 0.f, 0.f, 0.f);
    int beg = offs[i], end = offs[i + 1];
    for (int cb = beg; cb < end; cb += 64) {
        int cnt = end - cb;
        if (cnt > 64) cnt = 64;
        // phase 1: per-edge logits, lane = edge
        int src = 0;
        float e = -1e30f;
        if (lane < cnt) {
            src = csr[cb + lane];
            e = lrelu(als[src] + ad);
        }
        float cm = e;
#pragma unroll
        for (int off = 32; off; off >>= 1) cm = fmaxf(cm, __shfl_xor(cm, off));
        float mn = fmaxf(m, cm);
        float p = (lane < cnt) ? __expf(e - mn) : 0.f;
        float cs = p;
#pragma unroll
        for (int off = 32; off; off >>= 1) cs += __shfl_xor(cs, off);
        float sc = __expf(m - mn);  // <= 1
        s = fmaf(s, sc, cs);
        acc.x *= sc;
        acc.y *= sc;
        acc.z *= sc;
        acc.w *= sc;
        m = mn;
        // phase 2: quad-packed weighted gather; padding slots carry p=0 (src=0 row is
        // valid memory, contributes nothing)
        int iters = (cnt + 3) >> 2;
        for (int j = 0; j < iters; j++) {
            int e4 = j * 4 + q;
            int sj = __shfl(src, e4);
            float pj = __shfl(p, e4);
            float4 v = *(const float4*)(hw + (size_t)sj * 64 + c * 4);
            acc.x = fmaf(pj, v.x, acc.x);
            acc.y = fmaf(pj, v.y, acc.y);
            acc.z = fmaf(pj, v.z, acc.z);
            acc.w = fmaf(pj, v.w, acc.w);
        }
    }
    // reduce partial sums across the 4 quads (all lanes end with the full sum)
#pragma unroll
    for (int off = 16; off <= 32; off <<= 1) {
        acc.x += __shfl_xor(acc.x, off);
        acc.y += __shfl_xor(acc.y, off);
        acc.z += __shfl_xor(acc.z, off);
        acc.w += __shfl_xor(acc.w, off);
    }
    // self loop
    float ps = __expf(eself - m);
    s += ps;
    float4 hv = *(const float4*)(hw + (size_t)i * 64 + c * 4);
    acc.x = fmaf(ps, hv.x, acc.x);
    acc.y = fmaf(ps, hv.y, acc.y);
    acc.z = fmaf(ps, hv.z, acc.z);
    acc.w = fmaf(ps, hv.w, acc.w);
    float inv = 1.f / s;
    const float4 bq = *(const float4*)(bv + c * 4);
    float4 o;
    o.x = fminf(fmaxf(fmaf(acc.x, inv, bq.x), -1.f), 1.f);
    o.y = fminf(fmaxf(fmaf(acc.y, inv, bq.y), -1.f), 1.f);
    o.z = fminf(fmaxf(fmaf(acc.z, inv, bq.z), -1.f), 1.f);
    o.w = fminf(fmaxf(fmaf(acc.w, inv, bq.w), -1.f), 1.f);
    if (q == 0) *(float4*)(out + (size_t)i * 64 + c * 4) = o;
}

// ---------------- launch ----------------

extern "C" void kernel_launch(void* const* d_in, const int* in_sizes, int n_in, void* d_out, int out_size,
                              void* d_ws, size_t ws_size, hipStream_t stream) {
    const float* x = (const float*)d_in[0];
    const int* ei = (const int*)d_in[1];  // [2, NE] int32
    const float* W = (const float*)d_in[2];
    const float* a_s = (const float*)d_in[3];
    const float* a_d = (const float*)d_in[4];
    const float* b = (const float*)d_in[5];
    float* out = (float*)d_out;

    char* w = (char*)d_ws;
    auto alloc = [&](size_t bytes) -> char* {
        char* p = w;
        w += (bytes + 255) & ~(size_t)255;
        return p;
    };
    int* bcnt = (int*)alloc(256 * 4);
    int* bbase = (int*)alloc(257 * 4);
    int* bcur = (int*)alloc(256 * 4);
    int* offs = (int*)alloc((NN + 1) * 4);
    int* csr = (int*)alloc((size_t)NE * 4);
    // pairs (12.8 MB, CSR-build phase) aliases the als/ald/hwb region (layer phase)
    size_t layer_bytes = (size_t)(2 * NN + NN * DIM) * 4;
    size_t build_bytes = (size_t)NE * 8;
    char* region = alloc(layer_bytes > build_bytes ? layer_bytes : build_bytes);
    int2* pairs = (int2*)region;
    float* als = (float*)region;
    float* ald = als + NN;
    float* hwb = ald + NN;

    // CSR by dst (same inputs every call -> same work every call)
    hipMemsetAsync(bcnt, 0, 256 * 4, stream);
    k_bucket_hist<<<256, 256, 0, stream>>>(ei, bcnt);
    k_bucket_scan<<<1, 256, 0, stream>>>(bcnt, bbase, bcur, offs);
    k_partition<<<(NE + TILE - 1) / TILE, 256, 0, stream>>>(ei, bcur, pairs);
    k_node_csr<<<NBUCK, 256, 0, stream>>>(pairs, bbase, offs, csr);

    // 3 GAT layers; d_out doubles as the h ping buffer (h dead once hw computed)
    const float* hin = x;
    for (int l = 0; l < NL; l++) {
        k_transform<<<1600, 256, 0, stream>>>(hin, W + l * DIM * DIM, a_s + l * DIM, a_d + l * DIM, hwb, als, ald);
        k_aggregate<<<(NN + 3) / 4, 256, 0, stream>>>(hwb, als, ald, offs, csr, b + l * DIM, out);
        hin = out;
    }
}

// Round 6
// 424.724 us; speedup vs baseline: 1.3702x; 1.3702x over previous
//
#include <hip/hip_runtime.h>

#define NN 100000
#define NE 1600000
#define DIM 64
#define NL 3
#define SLOPE 0.2f

#define BSH 9                      // 512 nodes per bucket
#define NBUCK ((NN + 511) >> BSH)  // 196
#define EPT 16
#define TILE (256 * EPT)  // 4096 edges per partition tile
#define MT 128            // transform M-tile

static __device__ __forceinline__ float lrelu(float x) { return x > 0.f ? x : SLOPE * x; }

// ---------------- CSR build: LDS-binned two-level counting sort ----------------

// per-block LDS histogram over dst buckets, one global atomic per block x bucket
__global__ __launch_bounds__(256) void k_bucket_hist(const int* __restrict__ ei, int* __restrict__ bcnt) {
    __shared__ int h[256];
    int t = threadIdx.x;
    h[t] = 0;
    __syncthreads();
    for (int e = blockIdx.x * 256 + t; e < NE; e += 256 * 256) atomicAdd(&h[ei[NE + e] >> BSH], 1);
    __syncthreads();
    if (t < NBUCK && h[t]) atomicAdd(&bcnt[t], h[t]);
}

__global__ void k_bucket_scan(const int* __restrict__ bcnt, int* __restrict__ bbase, int* __restrict__ bcur,
                              int* __restrict__ offs) {
    __shared__ int sm[256];
    int t = threadIdx.x;
    sm[t] = (t < NBUCK) ? bcnt[t] : 0;
    __syncthreads();
    for (int off = 1; off < 256; off <<= 1) {
        int x = (t >= off) ? sm[t - off] : 0;
        __syncthreads();
        sm[t] += x;
        __syncthreads();
    }
    if (t < NBUCK) {
        int ex = (t == 0) ? 0 : sm[t - 1];
        bbase[t] = ex;
        bcur[t] = ex;
    }
    if (t == 0) {
        bbase[NBUCK] = NE;
        offs[NN] = NE;
    }
}

// rank tile edges per bucket in LDS, reorder tile so same-bucket edges are contiguous,
// claim global space (1 atomic per bucket per tile), copy out coalesced.
__global__ __launch_bounds__(256) void k_partition(const int* __restrict__ ei, int* __restrict__ bcur,
                                                   int2* __restrict__ pairs) {
    __shared__ int2 tile[TILE];
    __shared__ int cnt[256], ofsx[256], gdel[256], sm[256];
    int t = threadIdx.x;
    int ts = blockIdx.x * TILE;
    int tilecnt = NE - ts;
    if (tilecnt > TILE) tilecnt = TILE;
    cnt[t] = 0;
    __syncthreads();
    int srcv[EPT], dstv[EPT], rk[EPT];
#pragma unroll
    for (int k = 0; k < EPT; k++) {
        int e = ts + k * 256 + t;
        if (e < NE) {
            srcv[k] = ei[e];
            dstv[k] = ei[NE + e];
            rk[k] = atomicAdd(&cnt[dstv[k] >> BSH], 1);
        } else {
            rk[k] = -1;
        }
    }
    __syncthreads();
    sm[t] = cnt[t];
    __syncthreads();
    for (int off = 1; off < 256; off <<= 1) {
        int x = (t >= off) ? sm[t - off] : 0;
        __syncthreads();
        sm[t] += x;
        __syncthreads();
    }
    ofsx[t] = (t == 0) ? 0 : sm[t - 1];
    __syncthreads();
#pragma unroll
    for (int k = 0; k < EPT; k++) {
        if (rk[k] >= 0) tile[ofsx[dstv[k] >> BSH] + rk[k]] = make_int2(srcv[k], dstv[k]);
    }
    if (t < NBUCK && cnt[t]) gdel[t] = atomicAdd(&bcur[t], cnt[t]) - ofsx[t];
    __syncthreads();
    for (int i = t; i < tilecnt; i += 256) {
        int2 p = tile[i];
        pairs[gdel[p.y >> BSH] + i] = p;
    }
}

// one block per bucket: per-node counts + scan in LDS, then scatter src into the
// bucket's contiguous csr segment (L2-resident). Emits global offs coalesced.
__global__ __launch_bounds__(256) void k_node_csr(const int2* __restrict__ pairs, const int* __restrict__ bbase,
                                                  int* __restrict__ offs, int* __restrict__ csr) {
    __shared__ int deg[512], sofs[512], scur[512], sm[256];
    int t = threadIdx.x;
    int b = blockIdx.x;
    int nodeBase = b << BSH;
    int nNodes = NN - nodeBase;
    if (nNodes > 512) nNodes = 512;
    deg[t] = 0;
    deg[t + 256] = 0;
    __syncthreads();
    int ebeg = bbase[b], eend = bbase[b + 1];
    for (int i = ebeg + t; i < eend; i += 256) atomicAdd(&deg[pairs[i].y - nodeBase], 1);
    __syncthreads();
    int a0 = deg[2 * t], a1 = deg[2 * t + 1];
    sm[t] = a0 + a1;
    __syncthreads();
    for (int off = 1; off < 256; off <<= 1) {
        int x = (t >= off) ? sm[t - off] : 0;
        __syncthreads();
        sm[t] += x;
        __syncthreads();
    }
    int base = (t == 0) ? 0 : sm[t - 1];
    sofs[2 * t] = base;
    sofs[2 * t + 1] = base + a0;
    scur[2 * t] = 0;
    scur[2 * t + 1] = 0;
    __syncthreads();
    for (int n = t; n < nNodes; n += 256) offs[nodeBase + n] = ebeg + sofs[n];
    for (int i = ebeg + t; i < eend; i += 256) {
        int2 p = pairs[i];
        int ln = p.y - nodeBase;
        int r = atomicAdd(&scur[ln], 1);
        csr[ebeg + sofs[ln] + r] = p.x;
    }
}

// ---------------- per-layer passes ----------------

// LDS-tiled register-blocked GEMM: 128-node M-tile, thread tile 8 rows x 4 cols.
// sh pad-65: column reads sh[r][k] are 4-distinct-bank x 16-lane broadcast (conflict-
// free); W b128 row reads 2-way (free). Attention logits fused via quad-16 shfl reduce.
__global__ __launch_bounds__(256) void k_transform(const float* __restrict__ h, const float* __restrict__ W,
                                                   const float* __restrict__ avs, const float* __restrict__ avd,
                                                   float* __restrict__ hw, float* __restrict__ als,
                                                   float* __restrict__ ald) {
    __shared__ float sh[MT][65];
    __shared__ float sw[64][64];
    int t = threadIdx.x;
    int tx = t & 15, ty = t >> 4;
    int base = blockIdx.x * MT;
    int rows = NN - base;
    if (rows > MT) rows = MT;
    {
        const float4* Wv = (const float4*)W;
        float4* swv = (float4*)sw;
        for (int i = t; i < 1024; i += 256) swv[i] = Wv[i];
    }
    for (int i = t; i < MT * 16; i += 256) {
        int r = i >> 4, cs = i & 15;
        float4 v = (r < rows) ? *(const float4*)(h + (size_t)(base + r) * 64 + cs * 4)
                              : make_float4(0.f, 0.f, 0.f, 0.f);
        sh[r][cs * 4 + 0] = v.x;
        sh[r][cs * 4 + 1] = v.y;
        sh[r][cs * 4 + 2] = v.z;
        sh[r][cs * 4 + 3] = v.w;
    }
    __syncthreads();
    float acc[8][4] = {};
    int r0 = ty * 8;
#pragma unroll 4
    for (int k = 0; k < 64; k++) {
        float4 b = *(const float4*)(&sw[k][tx * 4]);
#pragma unroll
        for (int r = 0; r < 8; r++) {
            float a = sh[r0 + r][k];
            acc[r][0] = fmaf(a, b.x, acc[r][0]);
            acc[r][1] = fmaf(a, b.y, acc[r][1]);
            acc[r][2] = fmaf(a, b.z, acc[r][2]);
            acc[r][3] = fmaf(a, b.w, acc[r][3]);
        }
    }
    float4 as4 = *(const float4*)(avs + tx * 4);
    float4 ad4 = *(const float4*)(avd + tx * 4);
#pragma unroll
    for (int r = 0; r < 8; r++) {
        int row = r0 + r;
        bool ok = row < rows;
        if (ok) {
            float4 o = make_float4(acc[r][0], acc[r][1], acc[r][2], acc[r][3]);
            *(float4*)(hw + (size_t)(base + row) * 64 + tx * 4) = o;
        }
        float ps = acc[r][0] * as4.x + acc[r][1] * as4.y + acc[r][2] * as4.z + acc[r][3] * as4.w;
        float pd = acc[r][0] * ad4.x + acc[r][1] * ad4.y + acc[r][2] * ad4.z + acc[r][3] * ad4.w;
#pragma unroll
        for (int off = 1; off <= 8; off <<= 1) {
            ps += __shfl_xor(ps, off);
            pd += __shfl_xor(pd, off);
        }
        if (tx == 0 && ok) {
            als[base + row] = ps;
            ald[base + row] = pd;
        }
    }
}

// wave per dst node. Phase 1: lanes = edges (coalesced csr load, als gather, shfl
// softmax reductions). Phase 2: quad-packed gather — quad q of 16 lanes handles edge
// j+q, each lane loads float4 of the row (1 dwordx4 instr fetches 4 full rows/wave).
// Self loop deferred to the end with weight exp(e_self - m_final).
__global__ __launch_bounds__(256) void k_aggregate(const float* __restrict__ hw, const float* __restrict__ als,
                                                   const float* __restrict__ ald, const int* __restrict__ offs,
                                                   const int* __restrict__ csr, const float* __restrict__ bv,
                                                   float* __restrict__ out) {
    int t = threadIdx.x, wave = t >> 6, lane = t & 63;
    int i = blockIdx.x * 4 + wave;
    if (i >= NN) return;
    int q = lane >> 4, c = lane & 15;
    float ad = ald[i];
    float eself = lrelu(als[i] + ad);
    float m = eself;
    float s = 0.f;
    float4 acc = make_float4(0.f, 0.f, 0.f, 0.f);
    int beg = offs[i], end = offs[i + 1];
    for (int cb = beg; cb < end; cb += 64) {
        int cnt = end - cb;
        if (cnt > 64) cnt = 64;
        // phase 1: per-edge logits, lane = edge
        int src = 0;
        float e = -1e30f;
        if (lane < cnt) {
            src = csr[cb + lane];
            e = lrelu(als[src] + ad);
        }
        float cm = e;
#pragma unroll
        for (int off = 32; off; off >>= 1) cm = fmaxf(cm, __shfl_xor(cm, off));
        float mn = fmaxf(m, cm);
        float p = (lane < cnt) ? __expf(e - mn) : 0.f;
        float cs = p;
#pragma unroll
        for (int off = 32; off; off >>= 1) cs += __shfl_xor(cs, off);
        float sc = __expf(m - mn);  // <= 1
        s = fmaf(s, sc, cs);
        acc.x *= sc;
        acc.y *= sc;
        acc.z *= sc;
        acc.w *= sc;
        m = mn;
        // phase 2: quad-packed weighted gather; padding slots carry p=0 (src=0 row is
        // valid memory, contributes nothing)
        int iters = (cnt + 3) >> 2;
        for (int j = 0; j < iters; j++) {
            int e4 = j * 4 + q;
            int sj = __shfl(src, e4);
            float pj = __shfl(p, e4);
            float4 v = *(const float4*)(hw + (size_t)sj * 64 + c * 4);
            acc.x = fmaf(pj, v.x, acc.x);
            acc.y = fmaf(pj, v.y, acc.y);
            acc.z = fmaf(pj, v.z, acc.z);
            acc.w = fmaf(pj, v.w, acc.w);
        }
    }
    // reduce partial sums across the 4 quads (all lanes end with the full sum)
#pragma unroll
    for (int off = 16; off <= 32; off <<= 1) {
        acc.x += __shfl_xor(acc.x, off);
        acc.y += __shfl_xor(acc.y, off);
        acc.z += __shfl_xor(acc.z, off);
        acc.w += __shfl_xor(acc.w, off);
    }
    // self loop
    float ps = __expf(eself - m);
    s += ps;
    float4 hv = *(const float4*)(hw + (size_t)i * 64 + c * 4);
    acc.x = fmaf(ps, hv.x, acc.x);
    acc.y = fmaf(ps, hv.y, acc.y);
    acc.z = fmaf(ps, hv.z, acc.z);
    acc.w = fmaf(ps, hv.w, acc.w);
    float inv = 1.f / s;
    const float4 bq = *(const float4*)(bv + c * 4);
    float4 o;
    o.x = fminf(fmaxf(fmaf(acc.x, inv, bq.x), -1.f), 1.f);
    o.y = fminf(fmaxf(fmaf(acc.y, inv, bq.y), -1.f), 1.f);
    o.z = fminf(fmaxf(fmaf(acc.z, inv, bq.z), -1.f), 1.f);
    o.w = fminf(fmaxf(fmaf(acc.w, inv, bq.w), -1.f), 1.f);
    if (q == 0) *(float4*)(out + (size_t)i * 64 + c * 4) = o;
}

// ---------------- launch ----------------

extern "C" void kernel_launch(void* const* d_in, const int* in_sizes, int n_in, void* d_out, int out_size,
                              void* d_ws, size_t ws_size, hipStream_t stream) {
    const float* x = (const float*)d_in[0];
    const int* ei = (const int*)d_in[1];  // [2, NE] int32
    const float* W = (const float*)d_in[2];
    const float* a_s = (const float*)d_in[3];
    const float* a_d = (const float*)d_in[4];
    const float* b = (const float*)d_in[5];
    float* out = (float*)d_out;

    char* w = (char*)d_ws;
    auto alloc = [&](size_t bytes) -> char* {
        char* p = w;
        w += (bytes + 255) & ~(size_t)255;
        return p;
    };
    int* bcnt = (int*)alloc(256 * 4);
    int* bbase = (int*)alloc(257 * 4);
    int* bcur = (int*)alloc(256 * 4);
    int* offs = (int*)alloc((NN + 1) * 4);
    int* csr = (int*)alloc((size_t)NE * 4);
    // pairs (12.8 MB, CSR-build phase) aliases the als/ald/hwb region (layer phase)
    size_t layer_bytes = (size_t)(2 * NN + NN * DIM) * 4;
    size_t build_bytes = (size_t)NE * 8;
    char* region = alloc(layer_bytes > build_bytes ? layer_bytes : build_bytes);
    int2* pairs = (int2*)region;
    float* als = (float*)region;
    float* ald = als + NN;
    float* hwb = ald + NN;

    // CSR by dst (same inputs every call -> same work every call)
    hipMemsetAsync(bcnt, 0, 256 * 4, stream);
    k_bucket_hist<<<256, 256, 0, stream>>>(ei, bcnt);
    k_bucket_scan<<<1, 256, 0, stream>>>(bcnt, bbase, bcur, offs);
    k_partition<<<(NE + TILE - 1) / TILE, 256, 0, stream>>>(ei, bcur, pairs);
    k_node_csr<<<NBUCK, 256, 0, stream>>>(pairs, bbase, offs, csr);

    // 3 GAT layers; d_out doubles as the h ping buffer (h dead once hw computed)
    const float* hin = x;
    for (int l = 0; l < NL; l++) {
        k_transform<<<(NN + MT - 1) / MT, 256, 0, stream>>>(hin, W + l * DIM * DIM, a_s + l * DIM, a_d + l * DIM,
                                                            hwb, als, ald);
        k_aggregate<<<(NN + 3) / 4, 256, 0, stream>>>(hwb, als, ald, offs, csr, b + l * DIM, out);
        hin = out;
    }
}

// Round 7
// 357.793 us; speedup vs baseline: 1.6265x; 1.1871x over previous
//
#include <hip/hip_runtime.h>
#include <hip/hip_fp16.h>

#define NN 100000
#define NE 1600000
#define DIM 64
#define NL 3
#define SLOPE 0.2f

#define BSH 9                      // 512 nodes per bucket
#define NBUCK ((NN + 511) >> BSH)  // 196
#define EPT 16
#define TILE (256 * EPT)  // 4096 edges per partition tile
#define MT 128            // transform M-tile

static __device__ __forceinline__ float lrelu(float x) { return x > 0.f ? x : SLOPE * x; }

// load 4 dims of an fp16 hw row (8B) and widen to float4
static __device__ __forceinline__ float4 load_h4(const ushort* __restrict__ base, size_t off) {
    uint2 u = *(const uint2*)(base + off);
    __half2 h0 = __builtin_bit_cast(__half2, u.x);
    __half2 h1 = __builtin_bit_cast(__half2, u.y);
    float2 f0 = __half22float2(h0);
    float2 f1 = __half22float2(h1);
    return make_float4(f0.x, f0.y, f1.x, f1.y);
}

// ---------------- CSR build: LDS-binned two-level counting sort ----------------

// per-block LDS histogram over dst buckets, one global atomic per block x bucket
__global__ __launch_bounds__(256) void k_bucket_hist(const int* __restrict__ ei, int* __restrict__ bcnt) {
    __shared__ int h[256];
    int t = threadIdx.x;
    h[t] = 0;
    __syncthreads();
    for (int e = blockIdx.x * 256 + t; e < NE; e += 256 * 256) atomicAdd(&h[ei[NE + e] >> BSH], 1);
    __syncthreads();
    if (t < NBUCK && h[t]) atomicAdd(&bcnt[t], h[t]);
}

__global__ void k_bucket_scan(const int* __restrict__ bcnt, int* __restrict__ bbase, int* __restrict__ bcur,
                              int* __restrict__ offs) {
    __shared__ int sm[256];
    int t = threadIdx.x;
    sm[t] = (t < NBUCK) ? bcnt[t] : 0;
    __syncthreads();
    for (int off = 1; off < 256; off <<= 1) {
        int x = (t >= off) ? sm[t - off] : 0;
        __syncthreads();
        sm[t] += x;
        __syncthreads();
    }
    if (t < NBUCK) {
        int ex = (t == 0) ? 0 : sm[t - 1];
        bbase[t] = ex;
        bcur[t] = ex;
    }
    if (t == 0) {
        bbase[NBUCK] = NE;
        offs[NN] = NE;
    }
}

// rank tile edges per bucket in LDS, reorder tile so same-bucket edges are contiguous,
// claim global space (1 atomic per bucket per tile), copy out coalesced.
__global__ __launch_bounds__(256) void k_partition(const int* __restrict__ ei, int* __restrict__ bcur,
                                                   int2* __restrict__ pairs) {
    __shared__ int2 tile[TILE];
    __shared__ int cnt[256], ofsx[256], gdel[256], sm[256];
    int t = threadIdx.x;
    int ts = blockIdx.x * TILE;
    int tilecnt = NE - ts;
    if (tilecnt > TILE) tilecnt = TILE;
    cnt[t] = 0;
    __syncthreads();
    int srcv[EPT], dstv[EPT], rk[EPT];
#pragma unroll
    for (int k = 0; k < EPT; k++) {
        int e = ts + k * 256 + t;
        if (e < NE) {
            srcv[k] = ei[e];
            dstv[k] = ei[NE + e];
            rk[k] = atomicAdd(&cnt[dstv[k] >> BSH], 1);
        } else {
            rk[k] = -1;
        }
    }
    __syncthreads();
    sm[t] = cnt[t];
    __syncthreads();
    for (int off = 1; off < 256; off <<= 1) {
        int x = (t >= off) ? sm[t - off] : 0;
        __syncthreads();
        sm[t] += x;
        __syncthreads();
    }
    ofsx[t] = (t == 0) ? 0 : sm[t - 1];
    __syncthreads();
#pragma unroll
    for (int k = 0; k < EPT; k++) {
        if (rk[k] >= 0) tile[ofsx[dstv[k] >> BSH] + rk[k]] = make_int2(srcv[k], dstv[k]);
    }
    if (t < NBUCK && cnt[t]) gdel[t] = atomicAdd(&bcur[t], cnt[t]) - ofsx[t];
    __syncthreads();
    for (int i = t; i < tilecnt; i += 256) {
        int2 p = tile[i];
        pairs[gdel[p.y >> BSH] + i] = p;
    }
}

// one block per bucket: per-node counts + scan in LDS, then scatter src into the
// bucket's contiguous csr segment (L2-resident). Emits global offs coalesced.
__global__ __launch_bounds__(256) void k_node_csr(const int2* __restrict__ pairs, const int* __restrict__ bbase,
                                                  int* __restrict__ offs, int* __restrict__ csr) {
    __shared__ int deg[512], sofs[512], scur[512], sm[256];
    int t = threadIdx.x;
    int b = blockIdx.x;
    int nodeBase = b << BSH;
    int nNodes = NN - nodeBase;
    if (nNodes > 512) nNodes = 512;
    deg[t] = 0;
    deg[t + 256] = 0;
    __syncthreads();
    int ebeg = bbase[b], eend = bbase[b + 1];
    for (int i = ebeg + t; i < eend; i += 256) atomicAdd(&deg[pairs[i].y - nodeBase], 1);
    __syncthreads();
    int a0 = deg[2 * t], a1 = deg[2 * t + 1];
    sm[t] = a0 + a1;
    __syncthreads();
    for (int off = 1; off < 256; off <<= 1) {
        int x = (t >= off) ? sm[t - off] : 0;
        __syncthreads();
        sm[t] += x;
        __syncthreads();
    }
    int base = (t == 0) ? 0 : sm[t - 1];
    sofs[2 * t] = base;
    sofs[2 * t + 1] = base + a0;
    scur[2 * t] = 0;
    scur[2 * t + 1] = 0;
    __syncthreads();
    for (int n = t; n < nNodes; n += 256) offs[nodeBase + n] = ebeg + sofs[n];
    for (int i = ebeg + t; i < eend; i += 256) {
        int2 p = pairs[i];
        int ln = p.y - nodeBase;
        int r = atomicAdd(&scur[ln], 1);
        csr[ebeg + sofs[ln] + r] = p.x;
    }
}

// ---------------- per-layer passes ----------------

// LDS-tiled register-blocked GEMM: 128-node M-tile, thread tile 8 rows x 4 cols.
// Writes hw in fp16 (aggregation input); attention logits from fp32 acc (exact).
__global__ __launch_bounds__(256) void k_transform(const float* __restrict__ h, const float* __restrict__ W,
                                                   const float* __restrict__ avs, const float* __restrict__ avd,
                                                   ushort* __restrict__ hw, float* __restrict__ als,
                                                   float* __restrict__ ald) {
    __shared__ float sh[MT][65];
    __shared__ float sw[64][64];
    int t = threadIdx.x;
    int tx = t & 15, ty = t >> 4;
    int base = blockIdx.x * MT;
    int rows = NN - base;
    if (rows > MT) rows = MT;
    {
        const float4* Wv = (const float4*)W;
        float4* swv = (float4*)sw;
        for (int i = t; i < 1024; i += 256) swv[i] = Wv[i];
    }
    for (int i = t; i < MT * 16; i += 256) {
        int r = i >> 4, cs = i & 15;
        float4 v = (r < rows) ? *(const float4*)(h + (size_t)(base + r) * 64 + cs * 4)
                              : make_float4(0.f, 0.f, 0.f, 0.f);
        sh[r][cs * 4 + 0] = v.x;
        sh[r][cs * 4 + 1] = v.y;
        sh[r][cs * 4 + 2] = v.z;
        sh[r][cs * 4 + 3] = v.w;
    }
    __syncthreads();
    float acc[8][4] = {};
    int r0 = ty * 8;
#pragma unroll 4
    for (int k = 0; k < 64; k++) {
        float4 b = *(const float4*)(&sw[k][tx * 4]);
#pragma unroll
        for (int r = 0; r < 8; r++) {
            float a = sh[r0 + r][k];
            acc[r][0] = fmaf(a, b.x, acc[r][0]);
            acc[r][1] = fmaf(a, b.y, acc[r][1]);
            acc[r][2] = fmaf(a, b.z, acc[r][2]);
            acc[r][3] = fmaf(a, b.w, acc[r][3]);
        }
    }
    float4 as4 = *(const float4*)(avs + tx * 4);
    float4 ad4 = *(const float4*)(avd + tx * 4);
#pragma unroll
    for (int r = 0; r < 8; r++) {
        int row = r0 + r;
        bool ok = row < rows;
        if (ok) {
            __half2 h0 = __floats2half2_rn(acc[r][0], acc[r][1]);
            __half2 h1 = __floats2half2_rn(acc[r][2], acc[r][3]);
            uint2 u;
            u.x = __builtin_bit_cast(unsigned int, h0);
            u.y = __builtin_bit_cast(unsigned int, h1);
            *(uint2*)(hw + (size_t)(base + row) * 64 + tx * 4) = u;
        }
        float ps = acc[r][0] * as4.x + acc[r][1] * as4.y + acc[r][2] * as4.z + acc[r][3] * as4.w;
        float pd = acc[r][0] * ad4.x + acc[r][1] * ad4.y + acc[r][2] * ad4.z + acc[r][3] * ad4.w;
#pragma unroll
        for (int off = 1; off <= 8; off <<= 1) {
            ps += __shfl_xor(ps, off);
            pd += __shfl_xor(pd, off);
        }
        if (tx == 0 && ok) {
            als[base + row] = ps;
            ald[base + row] = pd;
        }
    }
}

// wave per dst node. Phase 1: lanes = edges (coalesced csr load, als gather, shfl
// softmax reductions). Phase 2: quad-packed fp16 gather with explicit 4-deep MLP:
// per step, 8 independent bpermutes broadcast 4 (src,p) pairs, then 4 independent
// 8B row loads issue before any use. Padding slots carry p=0 (row 0 is valid memory).
__global__ __launch_bounds__(256) void k_aggregate(const ushort* __restrict__ hw, const float* __restrict__ als,
                                                   const float* __restrict__ ald, const int* __restrict__ offs,
                                                   const int* __restrict__ csr, const float* __restrict__ bv,
                                                   float* __restrict__ out) {
    int t = threadIdx.x, wave = t >> 6, lane = t & 63;
    int i = blockIdx.x * 4 + wave;
    if (i >= NN) return;
    int q = lane >> 4, c = lane & 15;
    float ad = ald[i];
    float eself = lrelu(als[i] + ad);
    float m = eself;
    float s = 0.f;
    float4 acc = make_float4(0.f, 0.f, 0.f, 0.f);
    int beg = offs[i], end = offs[i + 1];
    for (int cb = beg; cb < end; cb += 64) {
        int cnt = end - cb;
        if (cnt > 64) cnt = 64;
        // phase 1: per-edge logits, lane = edge
        int src = 0;
        float e = -1e30f;
        if (lane < cnt) {
            src = csr[cb + lane];
            e = lrelu(als[src] + ad);
        }
        float cm = e;
#pragma unroll
        for (int off = 32; off; off >>= 1) cm = fmaxf(cm, __shfl_xor(cm, off));
        float mn = fmaxf(m, cm);
        float p = (lane < cnt) ? __expf(e - mn) : 0.f;
        float cs = p;
#pragma unroll
        for (int off = 32; off; off >>= 1) cs += __shfl_xor(cs, off);
        float sc = __expf(m - mn);  // <= 1
        s = fmaf(s, sc, cs);
        acc.x *= sc;
        acc.y *= sc;
        acc.z *= sc;
        acc.w *= sc;
        m = mn;
        // phase 2: 16 edges per step (4 per quad), 4 loads in flight
        int steps = (cnt + 15) >> 4;
        for (int st = 0; st < steps; st++) {
            int jb = st * 16 + q;
            int s0 = __shfl(src, jb);
            int s1 = __shfl(src, jb + 4);
            int s2 = __shfl(src, jb + 8);
            int s3 = __shfl(src, jb + 12);
            float p0 = __shfl(p, jb);
            float p1 = __shfl(p, jb + 4);
            float p2 = __shfl(p, jb + 8);
            float p3 = __shfl(p, jb + 12);
            float4 v0 = load_h4(hw, (size_t)s0 * 64 + c * 4);
            float4 v1 = load_h4(hw, (size_t)s1 * 64 + c * 4);
            float4 v2 = load_h4(hw, (size_t)s2 * 64 + c * 4);
            float4 v3 = load_h4(hw, (size_t)s3 * 64 + c * 4);
            acc.x = fmaf(p0, v0.x, acc.x);
            acc.y = fmaf(p0, v0.y, acc.y);
            acc.z = fmaf(p0, v0.z, acc.z);
            acc.w = fmaf(p0, v0.w, acc.w);
            acc.x = fmaf(p1, v1.x, acc.x);
            acc.y = fmaf(p1, v1.y, acc.y);
            acc.z = fmaf(p1, v1.z, acc.z);
            acc.w = fmaf(p1, v1.w, acc.w);
            acc.x = fmaf(p2, v2.x, acc.x);
            acc.y = fmaf(p2, v2.y, acc.y);
            acc.z = fmaf(p2, v2.z, acc.z);
            acc.w = fmaf(p2, v2.w, acc.w);
            acc.x = fmaf(p3, v3.x, acc.x);
            acc.y = fmaf(p3, v3.y, acc.y);
            acc.z = fmaf(p3, v3.z, acc.z);
            acc.w = fmaf(p3, v3.w, acc.w);
        }
    }
    // reduce partial sums across the 4 quads (all lanes end with the full sum)
#pragma unroll
    for (int off = 16; off <= 32; off <<= 1) {
        acc.x += __shfl_xor(acc.x, off);
        acc.y += __shfl_xor(acc.y, off);
        acc.z += __shfl_xor(acc.z, off);
        acc.w += __shfl_xor(acc.w, off);
    }
    // self loop
    float ps = __expf(eself - m);
    s += ps;
    float4 hv = load_h4(hw, (size_t)i * 64 + c * 4);
    acc.x = fmaf(ps, hv.x, acc.x);
    acc.y = fmaf(ps, hv.y, acc.y);
    acc.z = fmaf(ps, hv.z, acc.z);
    acc.w = fmaf(ps, hv.w, acc.w);
    float inv = 1.f / s;
    const float4 bq = *(const float4*)(bv + c * 4);
    float4 o;
    o.x = fminf(fmaxf(fmaf(acc.x, inv, bq.x), -1.f), 1.f);
    o.y = fminf(fmaxf(fmaf(acc.y, inv, bq.y), -1.f), 1.f);
    o.z = fminf(fmaxf(fmaf(acc.z, inv, bq.z), -1.f), 1.f);
    o.w = fminf(fmaxf(fmaf(acc.w, inv, bq.w), -1.f), 1.f);
    if (q == 0) *(float4*)(out + (size_t)i * 64 + c * 4) = o;
}

// ---------------- launch ----------------

extern "C" void kernel_launch(void* const* d_in, const int* in_sizes, int n_in, void* d_out, int out_size,
                              void* d_ws, size_t ws_size, hipStream_t stream) {
    const float* x = (const float*)d_in[0];
    const int* ei = (const int*)d_in[1];  // [2, NE] int32
    const float* W = (const float*)d_in[2];
    const float* a_s = (const float*)d_in[3];
    const float* a_d = (const float*)d_in[4];
    const float* b = (const float*)d_in[5];
    float* out = (float*)d_out;

    char* w = (char*)d_ws;
    auto alloc = [&](size_t bytes) -> char* {
        char* p = w;
        w += (bytes + 255) & ~(size_t)255;
        return p;
    };
    int* bcnt = (int*)alloc(256 * 4);
    int* bbase = (int*)alloc(257 * 4);
    int* bcur = (int*)alloc(256 * 4);
    int* offs = (int*)alloc((NN + 1) * 4);
    int* csr = (int*)alloc((size_t)NE * 4);
    // pairs (12.8 MB, CSR-build phase) aliases the als/ald/hw(fp16) region (layer phase)
    size_t layer_bytes = (size_t)(2 * NN) * 4 + (size_t)NN * DIM * 2;
    size_t build_bytes = (size_t)NE * 8;
    char* region = alloc(layer_bytes > build_bytes ? layer_bytes : build_bytes);
    int2* pairs = (int2*)region;
    float* als = (float*)region;
    float* ald = als + NN;
    ushort* hwb = (ushort*)(ald + NN);

    // CSR by dst (same inputs every call -> same work every call)
    hipMemsetAsync(bcnt, 0, 256 * 4, stream);
    k_bucket_hist<<<256, 256, 0, stream>>>(ei, bcnt);
    k_bucket_scan<<<1, 256, 0, stream>>>(bcnt, bbase, bcur, offs);
    k_partition<<<(NE + TILE - 1) / TILE, 256, 0, stream>>>(ei, bcur, pairs);
    k_node_csr<<<NBUCK, 256, 0, stream>>>(pairs, bbase, offs, csr);

    // 3 GAT layers; d_out doubles as the h ping buffer (h dead once hw computed)
    const float* hin = x;
    for (int l = 0; l < NL; l++) {
        k_transform<<<(NN + MT - 1) / MT, 256, 0, stream>>>(hin, W + l * DIM * DIM, a_s + l * DIM, a_d + l * DIM,
                                                            hwb, als, ald);
        k_aggregate<<<(NN + 3) / 4, 256, 0, stream>>>(hwb, als, ald, offs, csr, b + l * DIM, out);
        hin = out;
    }
}